// Round 1
// baseline (32.110 us; speedup 1.0000x reference)
//
#include <hip/hip_runtime.h>

// Cost volume: cost[b,i,h,w] = mean_c f1[b,c,h,w] * f2[b,c,h,w-i], i in [0,64), 0 if w<i.
// Shapes: B=4, C=128, H=128, W=256, lvls=64. fp32 in/out, bf16 MFMA compute.
//
// Structure: one workgroup per (b,h). Banded Gram G[p][w] = sum_c f2[c][p]*f1[c][w],
// band p in [w-63, w]. Wave j (of 8) owns w-tile [32j,32j+32) and its 3 p-tiles
// (tp=j-2..j) as 32x32 mfma_f32_32x32x16_bf16 tiles, K=128 in 8 steps of 16.
// Fragments loaded straight from global (coalesced dword, L1/L2 absorbs the 3x
// intra-block f2 reuse). Epilogue through LDS [i][w] for coalesced stores.

#define BDIM 4
#define CDIM 128
#define HDIM 128
#define WDIM 256
#define LVLS 64
#define HW   (HDIM * WDIM)          // 32768
#define CHW  (CDIM * HDIM * WDIM)   // 4194304

typedef short  bf16x8 __attribute__((ext_vector_type(8)));
typedef float  f32x16 __attribute__((ext_vector_type(16)));

__device__ __forceinline__ short f2bf(float f) {
    // fp32 -> bf16 round-to-nearest-even
    unsigned u = __builtin_bit_cast(unsigned, f);
    u += 0x7fffu + ((u >> 16) & 1u);
    return (short)(u >> 16);
}

__global__ __launch_bounds__(512, 4) void cost_volume_kernel(
    const float* __restrict__ f1, const float* __restrict__ f2,
    float* __restrict__ out)
{
    __shared__ float cost_lds[LVLS * WDIM];   // 64 KiB

    const int tid  = threadIdx.x;
    const int lane = tid & 63;
    const int wv   = tid >> 6;          // wave id 0..7
    const int wg   = blockIdx.x;        // 0..511
    const int b    = wg >> 7;
    const int h    = wg & (HDIM - 1);

    const float* __restrict__ f1bh = f1 + (size_t)b * CHW + (size_t)h * WDIM;
    const float* __restrict__ f2bh = f2 + (size_t)b * CHW + (size_t)h * WDIM;

    const int wl    = lane & 31;            // tile column 0..31
    const int wglob = wv * 32 + wl;         // this lane's output w
    const int koff  = (lane >> 5) * 8;      // k offset within K=16 step

    const int ntp = (wv < 2) ? (wv + 1) : 3;  // # of valid p-tiles (band clip at p>=0)
    const int tp0 = wv - (ntp - 1);           // first p-tile index

    f32x16 acc[3];
    #pragma unroll
    for (int t = 0; t < 3; ++t) acc[t] = (f32x16)0.0f;

    // ---- K loop: C=128 in 8 steps of K=16 ----
    #pragma unroll 2
    for (int kk = 0; kk < 8; ++kk) {
        const int kbase = kk * 16 + koff;

        // B fragment from f1: B[k][n=wglob], k = kbase..kbase+7
        bf16x8 bfrag;
        {
            const float* p1 = f1bh + (size_t)kbase * HW + wglob;
            #pragma unroll
            for (int jj = 0; jj < 8; ++jj)
                bfrag[jj] = f2bf(p1[(size_t)jj * HW]);
        }

        // A fragments from f2 (one per p-tile): A[m=p][k]
        #pragma unroll
        for (int t = 0; t < 3; ++t) {
            if (t < ntp) {
                const int tp = tp0 + t;
                bf16x8 afrag;
                const float* p2 = f2bh + (size_t)kbase * HW + (tp * 32 + wl);
                #pragma unroll
                for (int jj = 0; jj < 8; ++jj)
                    afrag[jj] = f2bf(p2[(size_t)jj * HW]);
                acc[t] = __builtin_amdgcn_mfma_f32_32x32x16_bf16(afrag, bfrag, acc[t], 0, 0, 0);
            }
        }
    }

    // ---- Epilogue: acc tiles -> LDS [i][w], zero-fill i>w, coalesced store ----

    // zero-fill triangle (only w<64 i.e. waves 0,1 have i>w cells)
    if (wv < 2 && lane < 32) {
        #pragma unroll 1
        for (int i = 1; i < LVLS; ++i)
            if (i > wglob) cost_lds[i * WDIM + wglob] = 0.0f;
    }

    // scatter accumulators: D row = (r&3) + 8*(r>>2) + 4*(lane>>5), col = lane&31
    const int rbase = 4 * (lane >> 5);
    #pragma unroll
    for (int t = 0; t < 3; ++t) {
        if (t < ntp) {
            const int tp = tp0 + t;
            #pragma unroll
            for (int r = 0; r < 16; ++r) {
                const int prow = tp * 32 + (r & 3) + 8 * (r >> 2) + rbase;
                const int i = wglob - prow;   // disparity
                if (i >= 0 && i < LVLS)
                    cost_lds[i * WDIM + wglob] = acc[t][r] * (1.0f / CDIM);
            }
        }
    }

    __syncthreads();

    // coalesced store: out[b][i][h][w]; LDS row i contiguous <-> global row i contiguous
    const size_t obase = ((size_t)b * LVLS) * HW + (size_t)h * WDIM;
    #pragma unroll
    for (int rep = 0; rep < 8; ++rep) {
        const int idx = rep * 512 + tid;      // 0..4095 float4s
        const int row = idx >> 6;             // i
        const int w4  = idx & 63;
        const float4 v = *reinterpret_cast<const float4*>(&cost_lds[row * WDIM + w4 * 4]);
        *reinterpret_cast<float4*>(out + obase + (size_t)row * HW + w4 * 4) = v;
    }
}

extern "C" void kernel_launch(void* const* d_in, const int* in_sizes, int n_in,
                              void* d_out, int out_size, void* d_ws, size_t ws_size,
                              hipStream_t stream) {
    const float* f1 = (const float*)d_in[0];
    const float* f2 = (const float*)d_in[1];
    float* out = (float*)d_out;
    cost_volume_kernel<<<dim3(BDIM * HDIM), dim3(512), 0, stream>>>(f1, f2, out);
}

// Round 2
// 31.938 us; speedup vs baseline: 1.0054x; 1.0054x over previous
//
#include <hip/hip_runtime.h>
#include <hip/hip_bf16.h>

// Cost volume: cost[b,i,h,w] = mean_c f1[b,c,h,w] * f2[b,c,h,w-i], i in [0,64), 0 if w<i.
// Shapes: B=4, C=128, H=128, W=256, lvls=64. fp32 in/out, bf16 MFMA compute.
//
// One workgroup per (b,h). Banded Gram G[p][w] = sum_c f2[c][p]*f1[c][w].
// Wave j (of 8) owns w-tile [32j,32j+32) and 3 p-tiles (tp=j-2..j) as 32x32
// mfma_f32_32x32x16_bf16 tiles, K=128 in 8 fully-unrolled steps of 16.
// BRANCH-FREE main loop: invalid p-tiles (tp<0, waves 0/1) are computed
// anyway on a clamped (valid) address and discarded in the epilogue, so the
// scheduler can software-pipeline loads across MFMAs. Epilogue stages the
// band into LDS [i][w] (diagonal scatter, stride 257 -> conflict-free) and
// stores fully coalesced float4.

#define BDIM 4
#define CDIM 128
#define HDIM 128
#define WDIM 256
#define LVLS 64
#define HW   (HDIM * WDIM)          // 32768
#define CHW  (CDIM * HDIM * WDIM)   // 4194304

typedef short  bf16x8 __attribute__((ext_vector_type(8)));
typedef float  f32x16 __attribute__((ext_vector_type(16)));

__device__ __forceinline__ short f2bf(float f) {
    __hip_bfloat16 h = __float2bfloat16(f);   // RNE; compiler may pack v_cvt_pk_bf16_f32
    return __builtin_bit_cast(short, h);
}

__global__ __launch_bounds__(512, 4) void cost_volume_kernel(
    const float* __restrict__ f1, const float* __restrict__ f2,
    float* __restrict__ out)
{
    __shared__ float cost_lds[LVLS * WDIM];   // 64 KiB

    const int tid  = threadIdx.x;
    const int lane = tid & 63;
    const int wv   = tid >> 6;          // wave id 0..7
    const int wg   = blockIdx.x;        // 0..511
    const int b    = wg >> 7;
    const int h    = wg & (HDIM - 1);

    const float* __restrict__ f1bh = f1 + (size_t)b * CHW + (size_t)h * WDIM;
    const float* __restrict__ f2bh = f2 + (size_t)b * CHW + (size_t)h * WDIM;

    const int wl    = lane & 31;            // tile column 0..31
    const int wglob = wv * 32 + wl;         // this lane's output w
    const int koff  = (lane >> 5) * 8;      // k offset within K=16 step

    // Tiles t=0..2 -> true tp = wv-2+t. Clamp address for tp<0 (garbage,
    // discarded in epilogue) so the main loop is branch-free.
    const int tp0c = (wv - 2 < 0) ? 0 : wv - 2;
    const int tp1c = (wv - 1 < 0) ? 0 : wv - 1;
    const int tp2c = wv;

    const float* pB  = f1bh + (size_t)koff * HW + wglob;
    const float* pA0 = f2bh + (size_t)koff * HW + tp0c * 32 + wl;
    const float* pA1 = f2bh + (size_t)koff * HW + tp1c * 32 + wl;
    const float* pA2 = f2bh + (size_t)koff * HW + tp2c * 32 + wl;

    f32x16 acc0 = (f32x16)0.0f, acc1 = (f32x16)0.0f, acc2 = (f32x16)0.0f;

    #pragma unroll
    for (int kk = 0; kk < 8; ++kk) {
        const size_t kb = (size_t)(kk * 16) * HW;

        float rb[8], ra0[8], ra1[8], ra2[8];
        #pragma unroll
        for (int j = 0; j < 8; ++j) rb[j]  = pB [kb + (size_t)j * HW];
        #pragma unroll
        for (int j = 0; j < 8; ++j) ra0[j] = pA0[kb + (size_t)j * HW];
        #pragma unroll
        for (int j = 0; j < 8; ++j) ra1[j] = pA1[kb + (size_t)j * HW];
        #pragma unroll
        for (int j = 0; j < 8; ++j) ra2[j] = pA2[kb + (size_t)j * HW];

        bf16x8 fb, fa0, fa1, fa2;
        #pragma unroll
        for (int j = 0; j < 8; ++j) {
            fb[j]  = f2bf(rb[j]);
            fa0[j] = f2bf(ra0[j]);
            fa1[j] = f2bf(ra1[j]);
            fa2[j] = f2bf(ra2[j]);
        }

        acc0 = __builtin_amdgcn_mfma_f32_32x32x16_bf16(fa0, fb, acc0, 0, 0, 0);
        acc1 = __builtin_amdgcn_mfma_f32_32x32x16_bf16(fa1, fb, acc1, 0, 0, 0);
        acc2 = __builtin_amdgcn_mfma_f32_32x32x16_bf16(fa2, fb, acc2, 0, 0, 0);
    }

    // ---- Epilogue ----

    // zero-fill triangle i > w (only w<64, i.e. waves 0,1)
    if (wv < 2 && lane < 32) {
        #pragma unroll 1
        for (int i = 1; i < LVLS; ++i)
            if (i > wglob) cost_lds[i * WDIM + wglob] = 0.0f;
    }

    // scatter valid tiles: D row = (r&3) + 8*(r>>2) + 4*(lane>>5), col = lane&31
    const int rbase = 4 * (lane >> 5);
    {
        const f32x16* accs[3] = { &acc0, &acc1, &acc2 };
        #pragma unroll
        for (int t = 0; t < 3; ++t) {
            const int tp = wv - 2 + t;
            if (tp >= 0) {
                const f32x16 a = *accs[t];
                #pragma unroll
                for (int r = 0; r < 16; ++r) {
                    const int prow = tp * 32 + (r & 3) + 8 * (r >> 2) + rbase;
                    const int i = wglob - prow;   // disparity
                    if (i >= 0 && i < LVLS)
                        cost_lds[i * WDIM + wglob] = a[r] * (1.0f / CDIM);
                }
            }
        }
    }

    __syncthreads();

    // coalesced store: out[b][i][h][w]; LDS row i contiguous <-> global row i contiguous
    const size_t obase = ((size_t)b * LVLS) * HW + (size_t)h * WDIM;
    #pragma unroll
    for (int rep = 0; rep < 8; ++rep) {
        const int idx = rep * 512 + tid;      // 0..4095 float4s
        const int row = idx >> 6;             // i
        const int w4  = idx & 63;
        const float4 v = *reinterpret_cast<const float4*>(&cost_lds[row * WDIM + w4 * 4]);
        *reinterpret_cast<float4*>(out + obase + (size_t)row * HW + w4 * 4) = v;
    }
}

extern "C" void kernel_launch(void* const* d_in, const int* in_sizes, int n_in,
                              void* d_out, int out_size, void* d_ws, size_t ws_size,
                              hipStream_t stream) {
    const float* f1 = (const float*)d_in[0];
    const float* f2 = (const float*)d_in[1];
    float* out = (float*)d_out;
    cost_volume_kernel<<<dim3(BDIM * HDIM), dim3(512), 0, stream>>>(f1, f2, out);
}